// Round 2
// baseline (599.100 us; speedup 1.0000x reference)
//
#include <hip/hip_runtime.h>
#include <hip/hip_bf16.h>

#define EMBD 1024
#define HEADS 16
#define DH 64
#define SEQ 2048
#define NBATCH 4
#define TOK (NBATCH*SEQ)

typedef __hip_bfloat16 bf16;
typedef __bf16 bf16x8 __attribute__((ext_vector_type(8)));
typedef float f32x4 __attribute__((ext_vector_type(4)));

// device-global scratch (no ws_size assumptions)
__device__ int g_isf32;
__device__ unsigned short g_Xb[TOK*EMBD];
__device__ unsigned short g_Wb[4][EMBD*EMBD];     // Wq, Wk, Wv, Wo as bf16
__device__ unsigned short g_Q[TOK*EMBD];
__device__ unsigned short g_K[TOK*EMBD];
__device__ unsigned short g_Vt[TOK*EMBD];
__device__ unsigned short g_O[TOK*EMBD];

__device__ __forceinline__ f32x4 mfma16(bf16x8 a, bf16x8 b, f32x4 c) {
    return __builtin_amdgcn_mfma_f32_16x16x32_bf16(a, b, c, 0, 0, 0);
}

#define GLL16(gp, lp) __builtin_amdgcn_global_load_lds( \
    (__attribute__((address_space(1))) void*)(gp), \
    (__attribute__((address_space(3))) void*)(lp), 16, 0, 0)

// ---------------------------------------------------------------------------
// Kernel 0a: dtype detect. f32 data: even u16 words are mantissa halves
// (random exponent pattern, ~12% in sane bf16 window). bf16 data: ~100%.
// ---------------------------------------------------------------------------
__global__ void detect_dtype(const unsigned short* __restrict__ Xu) {
    __shared__ int cnt;
    if (threadIdx.x == 0) cnt = 0;
    __syncthreads();
    int local = 0;
    for (int i = threadIdx.x; i < 1024; i += 256) {
        const unsigned e = (Xu[2*i] >> 7) & 0xFF;
        if (e >= 0x68 && e <= 0x86) local++;
    }
    atomicAdd(&cnt, local);
    __syncthreads();
    if (threadIdx.x == 0) g_isf32 = (cnt < 512) ? 1 : 0;
}

// ---------------------------------------------------------------------------
// Kernel 0b: convert (f32 -> bf16 RNE) or copy (bf16 -> bf16) X and 4 W's.
// One vec8 (8 elements) per thread.
// ---------------------------------------------------------------------------
__global__ void __launch_bounds__(256) cvt_all(
    const void* __restrict__ X, const void* __restrict__ Wq,
    const void* __restrict__ Wk, const void* __restrict__ Wv,
    const void* __restrict__ Wo)
{
    const int NV_X = TOK*EMBD/8;        // 1048576
    const int NV_W = EMBD*EMBD/8;       // 131072 = 2^17
    const long v = (long)blockIdx.x * 256 + threadIdx.x;
    const void* src; unsigned short* dst; long o;
    if (v < NV_X) { src = X; dst = g_Xb; o = v; }
    else {
        const long u = v - NV_X;
        const int wi = (int)(u >> 17);
        o = u & (NV_W - 1);
        src = (wi==0) ? Wq : (wi==1) ? Wk : (wi==2) ? Wv : Wo;
        dst = g_Wb[wi];
    }
    if (g_isf32) {
        const float4* sp = reinterpret_cast<const float4*>(src) + o*2;
        const float4 a = sp[0], b4 = sp[1];
        const float f[8] = {a.x, a.y, a.z, a.w, b4.x, b4.y, b4.z, b4.w};
        unsigned short r[8];
        #pragma unroll
        for (int i = 0; i < 8; ++i) {
            bf16 h = __float2bfloat16(f[i]);
            r[i] = *reinterpret_cast<unsigned short*>(&h);
        }
        *reinterpret_cast<uint4*>(dst + o*8) = *reinterpret_cast<const uint4*>(r);
    } else {
        *reinterpret_cast<uint4*>(dst + o*8) = reinterpret_cast<const uint4*>(src)[o];
    }
}

// ---------------------------------------------------------------------------
// Kernel 1: QKV projection.  out[t,e] = sum_k X[t,k]*W[e,k] + b[e]
// z=0: Q (scaled by 1/32, head-major), z=1: K (head-major), z=2: V^T.
// ---------------------------------------------------------------------------
__global__ void __launch_bounds__(256) qkv_gemm(
    const void* __restrict__ bq, const void* __restrict__ bk,
    const void* __restrict__ bv)
{
    const int z = blockIdx.z;
    const bf16* W    = reinterpret_cast<const bf16*>(g_Wb[z]);
    const void* bias = (z == 0) ? bq : (z == 1) ? bk : bv;
    const bf16* Xb   = reinterpret_cast<const bf16*>(g_Xb);
    const int  isf32 = g_isf32;

    const int tile_m = blockIdx.x * 128;
    const int tile_n = blockIdx.y * 128;
    const int tid  = threadIdx.x;
    const int lane = tid & 63;
    const int w    = tid >> 6;
    const int wr   = w >> 1, wc = w & 1;
    const int g    = lane >> 4, c = lane & 15;

    __shared__ __align__(16) bf16 As[128*64];
    __shared__ __align__(16) bf16 Bs[128*64];

    f32x4 acc[4][4] = {};

    for (int kk = 0; kk < EMBD; kk += 64) {
        const bf16* Ab = Xb + tile_m*EMBD + kk;
        const bf16* Bb = W  + tile_n*EMBD + kk;
        #pragma unroll
        for (int i = 0; i < 4; ++i) {
            const int li  = i*256 + tid;
            const int row = li >> 3;
            const int c8  = (li & 7) << 3;
            GLL16(Ab + row*EMBD + c8, As + li*8);
            GLL16(Bb + row*EMBD + c8, Bs + li*8);
        }
        __syncthreads();
        #pragma unroll
        for (int kh = 0; kh < 2; ++kh) {
            bf16x8 a[4], b[4];
            #pragma unroll
            for (int m = 0; m < 4; ++m)
                a[m] = *reinterpret_cast<const bf16x8*>(As + (wr*64 + m*16 + c)*64 + kh*32 + g*8);
            #pragma unroll
            for (int n = 0; n < 4; ++n)
                b[n] = *reinterpret_cast<const bf16x8*>(Bs + (wc*64 + n*16 + c)*64 + kh*32 + g*8);
            #pragma unroll
            for (int m = 0; m < 4; ++m)
                #pragma unroll
                for (int n = 0; n < 4; ++n)
                    acc[m][n] = mfma16(a[m], b[n], acc[m][n]);
        }
        __syncthreads();
    }

    const float scale = (z == 0) ? 0.03125f : 1.0f;   // fold 1/sqrt(EMBD) into Q
    bf16* Qp = reinterpret_cast<bf16*>(g_Q);
    bf16* Kp = reinterpret_cast<bf16*>(g_K);
    bf16* Vp = reinterpret_cast<bf16*>(g_Vt);

    #pragma unroll
    for (int n = 0; n < 4; ++n) {
        const int col = tile_n + wc*64 + n*16 + c;
        const float bval = isf32 ? reinterpret_cast<const float*>(bias)[col]
                                 : __bfloat162float(reinterpret_cast<const bf16*>(bias)[col]);
        const int h = col >> 6, d = col & 63;
        #pragma unroll
        for (int m = 0; m < 4; ++m) {
            const int row0 = tile_m + wr*64 + m*16 + g*4;
            #pragma unroll
            for (int r = 0; r < 4; ++r) {
                const int row = row0 + r;                 // token index
                const int bb = row >> 11, nn = row & (SEQ-1);
                const bf16 val = __float2bfloat16((acc[m][n][r] + bval) * scale);
                if (z == 0)      Qp[((bb*HEADS + h)*SEQ + nn)*DH + d] = val;
                else if (z == 1) Kp[((bb*HEADS + h)*SEQ + nn)*DH + d] = val;
                else             Vp[((bb*HEADS + h)*DH + d)*SEQ + nn] = val;
            }
        }
    }
}

// ---------------------------------------------------------------------------
// Kernel 2: flash attention.  One wave = 16 q rows of one (b,h).
// S layout: lane holds S[q=4g+r][kcol=c].  P bounced via LDS into A-frag.
// ---------------------------------------------------------------------------
__global__ void __launch_bounds__(256) attn_kernel()
{
    const int bh  = blockIdx.y;
    const int tid = threadIdx.x, lane = tid & 63, w = tid >> 6;
    const int g = lane >> 4, c = lane & 15;
    const int q0 = blockIdx.x*64 + w*16;

    const bf16* Qh = reinterpret_cast<const bf16*>(g_Q)  + bh*SEQ*DH;
    const bf16* Kh = reinterpret_cast<const bf16*>(g_K)  + bh*SEQ*DH;
    const bf16* Vh = reinterpret_cast<const bf16*>(g_Vt) + bh*DH*SEQ;
    bf16*       Oh = reinterpret_cast<bf16*>(g_O)        + bh*SEQ*DH;

    __shared__ __align__(16) bf16 Plds[4][16][32];   // per-wave P tile

    const bf16x8 aq0 = *reinterpret_cast<const bf16x8*>(Qh + (q0 + c)*DH + g*8);
    const bf16x8 aq1 = *reinterpret_cast<const bf16x8*>(Qh + (q0 + c)*DH + 32 + g*8);

    float mrow[4] = {-1e30f, -1e30f, -1e30f, -1e30f};
    float lsum[4] = {0.f, 0.f, 0.f, 0.f};
    f32x4 oacc[4] = {};

    for (int kt = 0; kt < SEQ; kt += 32) {
        const f32x4 zero = {};
        bf16x8 k00 = *reinterpret_cast<const bf16x8*>(Kh + (kt + c)*DH + g*8);
        bf16x8 k01 = *reinterpret_cast<const bf16x8*>(Kh + (kt + c)*DH + 32 + g*8);
        f32x4 s0 = mfma16(aq0, k00, zero); s0 = mfma16(aq1, k01, s0);
        bf16x8 k10 = *reinterpret_cast<const bf16x8*>(Kh + (kt + 16 + c)*DH + g*8);
        bf16x8 k11 = *reinterpret_cast<const bf16x8*>(Kh + (kt + 16 + c)*DH + 32 + g*8);
        f32x4 s1 = mfma16(aq0, k10, zero); s1 = mfma16(aq1, k11, s1);

        float tmax[4];
        #pragma unroll
        for (int r = 0; r < 4; ++r) tmax[r] = fmaxf(s0[r], s1[r]);
        #pragma unroll
        for (int msk = 1; msk < 16; msk <<= 1)
            #pragma unroll
            for (int r = 0; r < 4; ++r)
                tmax[r] = fmaxf(tmax[r], __shfl_xor(tmax[r], msk));

        float p0[4], p1[4], psum[4];
        #pragma unroll
        for (int r = 0; r < 4; ++r) {
            const float mn = fmaxf(mrow[r], tmax[r]);
            const float sc = __expf(mrow[r] - mn);
            p0[r] = __expf(s0[r] - mn);
            p1[r] = __expf(s1[r] - mn);
            psum[r] = p0[r] + p1[r];
            mrow[r] = mn;
            lsum[r] *= sc;
            #pragma unroll
            for (int dc = 0; dc < 4; ++dc) oacc[dc][r] *= sc;
        }
        #pragma unroll
        for (int msk = 1; msk < 16; msk <<= 1)
            #pragma unroll
            for (int r = 0; r < 4; ++r) psum[r] += __shfl_xor(psum[r], msk);
        #pragma unroll
        for (int r = 0; r < 4; ++r) lsum[r] += psum[r];

        #pragma unroll
        for (int r = 0; r < 4; ++r) {
            Plds[w][g*4 + r][c]      = __float2bfloat16(p0[r]);
            Plds[w][g*4 + r][16 + c] = __float2bfloat16(p1[r]);
        }
        // same-wave LDS RAW: DS pipeline processes in order; compiler orders may-alias
        const bf16x8 pa = *reinterpret_cast<const bf16x8*>(&Plds[w][c][g*8]);
        #pragma unroll
        for (int dc = 0; dc < 4; ++dc) {
            bf16x8 bv = *reinterpret_cast<const bf16x8*>(Vh + (dc*16 + c)*SEQ + kt + g*8);
            oacc[dc] = mfma16(pa, bv, oacc[dc]);
        }
    }

    #pragma unroll
    for (int r = 0; r < 4; ++r) {
        const float inv = 1.0f / lsum[r];
        #pragma unroll
        for (int dc = 0; dc < 4; ++dc)
            Oh[(q0 + g*4 + r)*DH + dc*16 + c] = __float2bfloat16(oacc[dc][r] * inv);
    }
}

// ---------------------------------------------------------------------------
// Kernel 3: output projection.  out[t,e] = sum_j Omerged[t,j]*Wo[e,j] + bo[e]
// BK=64 == DH, so each K-tile of the head-merged A is a contiguous block.
// ---------------------------------------------------------------------------
__global__ void __launch_bounds__(256) out_gemm(
    const void* __restrict__ bo, void* __restrict__ Out)
{
    const bf16* Oin = reinterpret_cast<const bf16*>(g_O);
    const bf16* Wo  = reinterpret_cast<const bf16*>(g_Wb[3]);
    const int isf32 = g_isf32;

    const int tile_m = blockIdx.x * 128;
    const int tile_n = blockIdx.y * 128;
    const int tid  = threadIdx.x;
    const int lane = tid & 63;
    const int w    = tid >> 6;
    const int wr   = w >> 1, wc = w & 1;
    const int g    = lane >> 4, c = lane & 15;

    __shared__ __align__(16) bf16 As[128*64];
    __shared__ __align__(16) bf16 Bs[128*64];

    f32x4 acc[4][4] = {};

    for (int kk = 0; kk < EMBD; kk += 64) {
        // A tile: rows = tokens tile_m..+128, head kk>>6 -> contiguous 128x64 block
        const bf16* Ab = Oin + ((((unsigned)tile_m >> 11)*HEADS + (kk >> 6))*SEQ + (tile_m & (SEQ-1)))*DH;
        const bf16* Bb = Wo + tile_n*EMBD + kk;
        #pragma unroll
        for (int i = 0; i < 4; ++i) {
            const int li  = i*256 + tid;
            const int row = li >> 3;
            const int c8  = (li & 7) << 3;
            GLL16(Ab + li*8, As + li*8);
            GLL16(Bb + row*EMBD + c8, Bs + li*8);
        }
        __syncthreads();
        #pragma unroll
        for (int kh = 0; kh < 2; ++kh) {
            bf16x8 a[4], b[4];
            #pragma unroll
            for (int m = 0; m < 4; ++m)
                a[m] = *reinterpret_cast<const bf16x8*>(As + (wr*64 + m*16 + c)*64 + kh*32 + g*8);
            #pragma unroll
            for (int n = 0; n < 4; ++n)
                b[n] = *reinterpret_cast<const bf16x8*>(Bs + (wc*64 + n*16 + c)*64 + kh*32 + g*8);
            #pragma unroll
            for (int m = 0; m < 4; ++m)
                #pragma unroll
                for (int n = 0; n < 4; ++n)
                    acc[m][n] = mfma16(a[m], b[n], acc[m][n]);
        }
        __syncthreads();
    }

    #pragma unroll
    for (int n = 0; n < 4; ++n) {
        const int col = tile_n + wc*64 + n*16 + c;
        const float bval = isf32 ? reinterpret_cast<const float*>(bo)[col]
                                 : __bfloat162float(reinterpret_cast<const bf16*>(bo)[col]);
        #pragma unroll
        for (int m = 0; m < 4; ++m) {
            const int row0 = tile_m + wr*64 + m*16 + g*4;
            #pragma unroll
            for (int r = 0; r < 4; ++r) {
                const float val = acc[m][n][r] + bval;
                const int idx = (row0 + r)*EMBD + col;
                if (isf32) reinterpret_cast<float*>(Out)[idx] = val;
                else       reinterpret_cast<bf16*>(Out)[idx] = __float2bfloat16(val);
            }
        }
    }
}

// ---------------------------------------------------------------------------
extern "C" void kernel_launch(void* const* d_in, const int* in_sizes, int n_in,
                              void* d_out, int out_size, void* d_ws, size_t ws_size,
                              hipStream_t stream) {
    (void)in_sizes; (void)n_in; (void)out_size; (void)d_ws; (void)ws_size;
    const void* X  = d_in[0];
    const void* Wq = d_in[1];
    const void* bq = d_in[2];
    const void* Wk = d_in[3];
    const void* bk = d_in[4];
    const void* Wv = d_in[5];
    const void* bv = d_in[6];
    const void* Wo = d_in[7];
    const void* bo = d_in[8];

    detect_dtype<<<dim3(1), dim3(256), 0, stream>>>((const unsigned short*)X);
    cvt_all<<<dim3((TOK*EMBD/8 + 4*EMBD*EMBD/8)/256), dim3(256), 0, stream>>>(X, Wq, Wk, Wv, Wo);
    qkv_gemm<<<dim3(TOK/128, EMBD/128, 3), dim3(256), 0, stream>>>(bq, bk, bv);
    attn_kernel<<<dim3(SEQ/64, NBATCH*HEADS), dim3(256), 0, stream>>>();
    out_gemm<<<dim3(TOK/128, EMBD/128), dim3(256), 0, stream>>>(bo, d_out);
}

// Round 3
// 419.288 us; speedup vs baseline: 1.4289x; 1.4289x over previous
//
#include <hip/hip_runtime.h>
#include <hip/hip_bf16.h>

#define EMBD 1024
#define HEADS 16
#define DH 64
#define SEQ 2048
#define NBATCH 4
#define TOK (NBATCH*SEQ)

typedef __hip_bfloat16 bf16;
typedef __bf16 bf16x8 __attribute__((ext_vector_type(8)));
typedef float f32x4 __attribute__((ext_vector_type(4)));
typedef float f32x16 __attribute__((ext_vector_type(16)));
typedef unsigned u32x4 __attribute__((ext_vector_type(4)));

// device-global scratch (no ws_size assumptions)
__device__ int g_isf32;
__device__ unsigned short g_Xb[TOK*EMBD];
__device__ unsigned short g_Wb[4][EMBD*EMBD];     // Wq, Wk, Wv, Wo as bf16
__device__ unsigned short g_Q[TOK*EMBD];
__device__ unsigned short g_K[TOK*EMBD];
__device__ unsigned short g_Vt[TOK*EMBD];
__device__ unsigned short g_O[TOK*EMBD];

__device__ __forceinline__ f32x4 mfma16(bf16x8 a, bf16x8 b, f32x4 c) {
    return __builtin_amdgcn_mfma_f32_16x16x32_bf16(a, b, c, 0, 0, 0);
}
__device__ __forceinline__ f32x16 mfma32(bf16x8 a, bf16x8 b, f32x16 c) {
    return __builtin_amdgcn_mfma_f32_32x32x16_bf16(a, b, c, 0, 0, 0);
}

#define GLL16(gp, lp) __builtin_amdgcn_global_load_lds( \
    (__attribute__((address_space(1))) void*)(gp), \
    (__attribute__((address_space(3))) void*)(lp), 16, 0, 0)

// ---------------------------------------------------------------------------
// Kernel 0a: dtype detect. f32 data: even u16 words are mantissa halves
// (random exponent pattern, ~12% in sane bf16 window). bf16 data: ~100%.
// ---------------------------------------------------------------------------
__global__ void detect_dtype(const unsigned short* __restrict__ Xu) {
    __shared__ int cnt;
    if (threadIdx.x == 0) cnt = 0;
    __syncthreads();
    int local = 0;
    for (int i = threadIdx.x; i < 1024; i += 256) {
        const unsigned e = (Xu[2*i] >> 7) & 0xFF;
        if (e >= 0x68 && e <= 0x86) local++;
    }
    atomicAdd(&cnt, local);
    __syncthreads();
    if (threadIdx.x == 0) g_isf32 = (cnt < 512) ? 1 : 0;
}

// ---------------------------------------------------------------------------
// Kernel 0b: convert (f32 -> bf16 RNE) or copy (bf16 -> bf16) X and 4 W's.
// ---------------------------------------------------------------------------
__global__ void __launch_bounds__(256) cvt_all(
    const void* __restrict__ X, const void* __restrict__ Wq,
    const void* __restrict__ Wk, const void* __restrict__ Wv,
    const void* __restrict__ Wo)
{
    const int NV_X = TOK*EMBD/8;        // 1048576
    const int NV_W = EMBD*EMBD/8;       // 131072 = 2^17
    const long v = (long)blockIdx.x * 256 + threadIdx.x;
    const void* src; unsigned short* dst; long o;
    if (v < NV_X) { src = X; dst = g_Xb; o = v; }
    else {
        const long u = v - NV_X;
        const int wi = (int)(u >> 17);
        o = u & (NV_W - 1);
        src = (wi==0) ? Wq : (wi==1) ? Wk : (wi==2) ? Wv : Wo;
        dst = g_Wb[wi];
    }
    if (g_isf32) {
        const float4* sp = reinterpret_cast<const float4*>(src) + o*2;
        const float4 a = sp[0], b4 = sp[1];
        const float f[8] = {a.x, a.y, a.z, a.w, b4.x, b4.y, b4.z, b4.w};
        unsigned short r[8];
        #pragma unroll
        for (int i = 0; i < 8; ++i) {
            bf16 h = __float2bfloat16(f[i]);
            r[i] = *reinterpret_cast<unsigned short*>(&h);
        }
        *reinterpret_cast<uint4*>(dst + o*8) = *reinterpret_cast<const uint4*>(r);
    } else {
        *reinterpret_cast<uint4*>(dst + o*8) = reinterpret_cast<const uint4*>(src)[o];
    }
}

// ---------------------------------------------------------------------------
// Kernel 1: QKV projection.  out[t,e] = sum_k X[t,k]*W[e,k] + b[e]
// z=0: Q (scaled by 1/32, head-major), z=1: K (head-major), z=2: V^T.
// ---------------------------------------------------------------------------
__global__ void __launch_bounds__(256) qkv_gemm(
    const void* __restrict__ bq, const void* __restrict__ bk,
    const void* __restrict__ bv)
{
    const int z = blockIdx.z;
    const bf16* W    = reinterpret_cast<const bf16*>(g_Wb[z]);
    const void* bias = (z == 0) ? bq : (z == 1) ? bk : bv;
    const bf16* Xb   = reinterpret_cast<const bf16*>(g_Xb);
    const int  isf32 = g_isf32;

    const int tile_m = blockIdx.x * 128;
    const int tile_n = blockIdx.y * 128;
    const int tid  = threadIdx.x;
    const int lane = tid & 63;
    const int w    = tid >> 6;
    const int wr   = w >> 1, wc = w & 1;
    const int g    = lane >> 4, c = lane & 15;

    __shared__ __align__(16) bf16 As[128*64];
    __shared__ __align__(16) bf16 Bs[128*64];

    f32x4 acc[4][4] = {};

    for (int kk = 0; kk < EMBD; kk += 64) {
        const bf16* Ab = Xb + tile_m*EMBD + kk;
        const bf16* Bb = W  + tile_n*EMBD + kk;
        #pragma unroll
        for (int i = 0; i < 4; ++i) {
            const int li  = i*256 + tid;
            const int row = li >> 3;
            const int c8  = (li & 7) << 3;
            GLL16(Ab + row*EMBD + c8, As + li*8);
            GLL16(Bb + row*EMBD + c8, Bs + li*8);
        }
        __syncthreads();
        #pragma unroll
        for (int kh = 0; kh < 2; ++kh) {
            bf16x8 a[4], b[4];
            #pragma unroll
            for (int m = 0; m < 4; ++m)
                a[m] = *reinterpret_cast<const bf16x8*>(As + (wr*64 + m*16 + c)*64 + kh*32 + g*8);
            #pragma unroll
            for (int n = 0; n < 4; ++n)
                b[n] = *reinterpret_cast<const bf16x8*>(Bs + (wc*64 + n*16 + c)*64 + kh*32 + g*8);
            #pragma unroll
            for (int m = 0; m < 4; ++m)
                #pragma unroll
                for (int n = 0; n < 4; ++n)
                    acc[m][n] = mfma16(a[m], b[n], acc[m][n]);
        }
        __syncthreads();
    }

    const float scale = (z == 0) ? 0.03125f : 1.0f;   // fold 1/sqrt(EMBD) into Q
    bf16* Qp = reinterpret_cast<bf16*>(g_Q);
    bf16* Kp = reinterpret_cast<bf16*>(g_K);
    bf16* Vp = reinterpret_cast<bf16*>(g_Vt);

    #pragma unroll
    for (int n = 0; n < 4; ++n) {
        const int col = tile_n + wc*64 + n*16 + c;
        const float bval = isf32 ? reinterpret_cast<const float*>(bias)[col]
                                 : __bfloat162float(reinterpret_cast<const bf16*>(bias)[col]);
        const int h = col >> 6, d = col & 63;
        #pragma unroll
        for (int m = 0; m < 4; ++m) {
            const int row0 = tile_m + wr*64 + m*16 + g*4;
            #pragma unroll
            for (int r = 0; r < 4; ++r) {
                const int row = row0 + r;                 // token index
                const int bb = row >> 11, nn = row & (SEQ-1);
                const bf16 val = __float2bfloat16((acc[m][n][r] + bval) * scale);
                if (z == 0)      Qp[((bb*HEADS + h)*SEQ + nn)*DH + d] = val;
                else if (z == 1) Kp[((bb*HEADS + h)*SEQ + nn)*DH + d] = val;
                else             Vp[((bb*HEADS + h)*DH + d)*SEQ + nn] = val;
            }
        }
    }
}

// ---------------------------------------------------------------------------
// Kernel 2: flash attention, swapped-QK^T 32x32x16 structure (m214 recipe).
// 1 wave = 32 q-rows; lane owns q = lane&31; P stays in registers.
// No LDS, no barriers. K/V read from global (L2-resident, 512KB/head).
// S = mfma(K, Q): C[row=k][col=q]; lane has 16 k-vals, partner lane+32 rest.
// PV: O^T = mfma(V^T, P^T) via cvt-pack + v_permlane32_swap_b32 fragments.
// ---------------------------------------------------------------------------
__device__ __forceinline__ unsigned pk2(float lo, float hi) {
    bf16 a = __float2bfloat16(lo), b = __float2bfloat16(hi);
    return (unsigned)*reinterpret_cast<unsigned short*>(&a)
         | ((unsigned)*reinterpret_cast<unsigned short*>(&b) << 16);
}

__global__ void __launch_bounds__(256) attn_kernel()
{
    const int bh  = blockIdx.y;
    const int tid = threadIdx.x, lane = tid & 63, wv = tid >> 6;
    const int ql = lane & 31, hi = lane >> 5;
    const int q0 = blockIdx.x*128 + wv*32;

    const bf16* Qh = reinterpret_cast<const bf16*>(g_Q)  + bh*SEQ*DH;
    const bf16* Kh = reinterpret_cast<const bf16*>(g_K)  + bh*SEQ*DH;
    const bf16* Vh = reinterpret_cast<const bf16*>(g_Vt) + bh*DH*SEQ;
    bf16*       Oh = reinterpret_cast<bf16*>(g_O)        + bh*SEQ*DH;

    // Q fragments (B-operand): lane holds Q[q0+ql][d = 16*sd + 8*hi + j]
    bf16x8 qf[4];
    #pragma unroll
    for (int sd = 0; sd < 4; ++sd)
        qf[sd] = *reinterpret_cast<const bf16x8*>(Qh + (q0 + ql)*DH + sd*16 + hi*8);

    float m = -1e30f, lsum = 0.f;
    f32x16 oacc[2] = {};

    for (int kt = 0; kt < SEQ; kt += 64) {
        // ---- QK^T: S[k][q], two 32-k tiles --------------------------------
        f32x16 s[2];
        #pragma unroll
        for (int t = 0; t < 2; ++t) {
            f32x16 acc = {};
            #pragma unroll
            for (int sd = 0; sd < 4; ++sd) {
                bf16x8 kf = *reinterpret_cast<const bf16x8*>(
                    Kh + (kt + 32*t + ql)*DH + sd*16 + hi*8);
                acc = mfma32(kf, qf[sd], acc);
            }
            s[t] = acc;
        }

        // ---- online softmax (lane-local row; 1 cross-lane shuffle) --------
        float mx8[8];
        #pragma unroll
        for (int r = 0; r < 8; ++r)
            mx8[r] = fmaxf(fmaxf(s[0][r], s[0][r+8]), fmaxf(s[1][r], s[1][r+8]));
        float mx4a = fmaxf(mx8[0], mx8[4]), mx4b = fmaxf(mx8[1], mx8[5]);
        float mx4c = fmaxf(mx8[2], mx8[6]), mx4d = fmaxf(mx8[3], mx8[7]);
        float mx = fmaxf(fmaxf(mx4a, mx4b), fmaxf(mx4c, mx4d));
        mx = fmaxf(mx, __shfl_xor(mx, 32));

        const float mn = fmaxf(m, mx);
        const float sc = __expf(m - mn);
        m = mn;

        float p[2][16];
        #pragma unroll
        for (int t = 0; t < 2; ++t)
            #pragma unroll
            for (int r = 0; r < 16; ++r)
                p[t][r] = __expf(s[t][r] - mn);

        float s8[8];
        #pragma unroll
        for (int r = 0; r < 8; ++r)
            s8[r] = (p[0][r] + p[0][r+8]) + (p[1][r] + p[1][r+8]);
        float ps = ((s8[0]+s8[4]) + (s8[1]+s8[5])) + ((s8[2]+s8[6]) + (s8[3]+s8[7]));
        ps += __shfl_xor(ps, 32);
        lsum = lsum*sc + ps;

        #pragma unroll
        for (int mt = 0; mt < 2; ++mt)
            #pragma unroll
            for (int r = 0; r < 16; ++r)
                oacc[mt][r] *= sc;

        // ---- P -> bf16 B-fragments via permlane32_swap --------------------
        // lane-local p[t][reg]: k = 32t + (reg&3) + 8*(reg>>2) + 4*hi
        // target frag pb[ss]: lane holds P^T[k=16ss+8*hi+j][q], j=0..7
        bf16x8 pb[4];
        #pragma unroll
        for (int ss = 0; ss < 4; ++ss) {
            const int t = ss >> 1, b0 = (ss & 1)*2, b1 = b0 + 1;
            unsigned x0 = pk2(p[t][4*b0+0], p[t][4*b0+1]);
            unsigned y0 = pk2(p[t][4*b1+0], p[t][4*b1+1]);
            asm("v_permlane32_swap_b32 %0, %1" : "+v"(x0), "+v"(y0));
            unsigned x1 = pk2(p[t][4*b0+2], p[t][4*b0+3]);
            unsigned y1 = pk2(p[t][4*b1+2], p[t][4*b1+3]);
            asm("v_permlane32_swap_b32 %0, %1" : "+v"(x1), "+v"(y1));
            u32x4 wvec = {x0, x1, y0, y1};
            pb[ss] = __builtin_bit_cast(bf16x8, wvec);
        }

        // ---- PV: O^T[d][q] += V^T-tile . P^T ------------------------------
        #pragma unroll
        for (int mt = 0; mt < 2; ++mt) {
            #pragma unroll
            for (int ss = 0; ss < 4; ++ss) {
                bf16x8 vf = *reinterpret_cast<const bf16x8*>(
                    Vh + (32*mt + ql)*SEQ + kt + ss*16 + hi*8);
                oacc[mt] = mfma32(vf, pb[ss], oacc[mt]);
            }
        }
    }

    // ---- epilogue: O[q][d] = O^T/lsum ------------------------------------
    const float inv = 1.0f / lsum;
    #pragma unroll
    for (int mt = 0; mt < 2; ++mt) {
        #pragma unroll
        for (int b = 0; b < 4; ++b) {
            const int d0 = 32*mt + 8*b + 4*hi;
            unsigned short r4[4];
            #pragma unroll
            for (int t = 0; t < 4; ++t) {
                bf16 h = __float2bfloat16(oacc[mt][4*b + t] * inv);
                r4[t] = *reinterpret_cast<unsigned short*>(&h);
            }
            *reinterpret_cast<ushort4*>(Oh + (q0 + ql)*DH + d0) =
                *reinterpret_cast<const ushort4*>(r4);
        }
    }
}

// ---------------------------------------------------------------------------
// Kernel 3: output projection.  out[t,e] = sum_j Omerged[t,j]*Wo[e,j] + bo[e]
// ---------------------------------------------------------------------------
__global__ void __launch_bounds__(256) out_gemm(
    const void* __restrict__ bo, void* __restrict__ Out)
{
    const bf16* Oin = reinterpret_cast<const bf16*>(g_O);
    const bf16* Wo  = reinterpret_cast<const bf16*>(g_Wb[3]);
    const int isf32 = g_isf32;

    const int tile_m = blockIdx.x * 128;
    const int tile_n = blockIdx.y * 128;
    const int tid  = threadIdx.x;
    const int lane = tid & 63;
    const int w    = tid >> 6;
    const int wr   = w >> 1, wc = w & 1;
    const int g    = lane >> 4, c = lane & 15;

    __shared__ __align__(16) bf16 As[128*64];
    __shared__ __align__(16) bf16 Bs[128*64];

    f32x4 acc[4][4] = {};

    for (int kk = 0; kk < EMBD; kk += 64) {
        const bf16* Ab = Oin + ((((unsigned)tile_m >> 11)*HEADS + (kk >> 6))*SEQ + (tile_m & (SEQ-1)))*DH;
        const bf16* Bb = Wo + tile_n*EMBD + kk;
        #pragma unroll
        for (int i = 0; i < 4; ++i) {
            const int li  = i*256 + tid;
            const int row = li >> 3;
            const int c8  = (li & 7) << 3;
            GLL16(Ab + li*8, As + li*8);
            GLL16(Bb + row*EMBD + c8, Bs + li*8);
        }
        __syncthreads();
        #pragma unroll
        for (int kh = 0; kh < 2; ++kh) {
            bf16x8 a[4], b[4];
            #pragma unroll
            for (int m = 0; m < 4; ++m)
                a[m] = *reinterpret_cast<const bf16x8*>(As + (wr*64 + m*16 + c)*64 + kh*32 + g*8);
            #pragma unroll
            for (int n = 0; n < 4; ++n)
                b[n] = *reinterpret_cast<const bf16x8*>(Bs + (wc*64 + n*16 + c)*64 + kh*32 + g*8);
            #pragma unroll
            for (int m = 0; m < 4; ++m)
                #pragma unroll
                for (int n = 0; n < 4; ++n)
                    acc[m][n] = mfma16(a[m], b[n], acc[m][n]);
        }
        __syncthreads();
    }

    #pragma unroll
    for (int n = 0; n < 4; ++n) {
        const int col = tile_n + wc*64 + n*16 + c;
        const float bval = isf32 ? reinterpret_cast<const float*>(bo)[col]
                                 : __bfloat162float(reinterpret_cast<const bf16*>(bo)[col]);
        #pragma unroll
        for (int m = 0; m < 4; ++m) {
            const int row0 = tile_m + wr*64 + m*16 + g*4;
            #pragma unroll
            for (int r = 0; r < 4; ++r) {
                const float val = acc[m][n][r] + bval;
                const int idx = (row0 + r)*EMBD + col;
                if (isf32) reinterpret_cast<float*>(Out)[idx] = val;
                else       reinterpret_cast<bf16*>(Out)[idx] = __float2bfloat16(val);
            }
        }
    }
}

// ---------------------------------------------------------------------------
extern "C" void kernel_launch(void* const* d_in, const int* in_sizes, int n_in,
                              void* d_out, int out_size, void* d_ws, size_t ws_size,
                              hipStream_t stream) {
    (void)in_sizes; (void)n_in; (void)out_size; (void)d_ws; (void)ws_size;
    const void* X  = d_in[0];
    const void* Wq = d_in[1];
    const void* bq = d_in[2];
    const void* Wk = d_in[3];
    const void* bk = d_in[4];
    const void* Wv = d_in[5];
    const void* bv = d_in[6];
    const void* Wo = d_in[7];
    const void* bo = d_in[8];

    detect_dtype<<<dim3(1), dim3(256), 0, stream>>>((const unsigned short*)X);
    cvt_all<<<dim3((TOK*EMBD/8 + 4*EMBD*EMBD/8)/256), dim3(256), 0, stream>>>(X, Wq, Wk, Wv, Wo);
    qkv_gemm<<<dim3(TOK/128, EMBD/128, 3), dim3(256), 0, stream>>>(bq, bk, bv);
    attn_kernel<<<dim3(SEQ/128, NBATCH*HEADS), dim3(256), 0, stream>>>();
    out_gemm<<<dim3(TOK/128, EMBD/128), dim3(256), 0, stream>>>(bo, d_out);
}